// Round 1
// baseline (49.789 us; speedup 1.0000x reference)
//
#include <hip/hip_runtime.h>
#include <stdint.h>

// One thread per (batch, row). Input mask is binary float32 (exactly 0.0f or
// 1.0f). We treat words as uint32 bit-patterns: nonzero == digit possible.
//
// Per row logic (derived from the reference's conv/compare chain):
//   cand[w]   = 9-bit mask of possible digits at cell w
//   naked pair = cell whose cand has popcount 2
//   For each pair-value pm occurring EXACTLY twice in the row:
//     every cell w with cand[w] != pm gets digits of pm erased.
//   out bit (d,w) = cand[w] & ~clear[w], emitted as 1.0f / 0.0f bit patterns.

__global__ __launch_bounds__(256) void sudoku_rows_kernel(
    const uint32_t* __restrict__ in, uint32_t* __restrict__ out, int nrows) {
  int gid = blockIdx.x * blockDim.x + threadIdx.x;
  if (gid >= nrows) return;
  int b = gid / 9;
  int h = gid - b * 9;
  const uint32_t* base = in + (size_t)b * 729 + h * 9;  // + d*81 + w

  // Build per-cell candidate bitmasks.
  uint32_t cand[9];
#pragma unroll
  for (int w = 0; w < 9; ++w) cand[w] = 0u;
#pragma unroll
  for (int d = 0; d < 9; ++d) {
    uint32_t tmp[9];
    __builtin_memcpy(tmp, base + d * 81, 36);  // 9 contiguous words
#pragma unroll
    for (int w = 0; w < 9; ++w) cand[w] |= (tmp[w] ? 1u : 0u) << d;
  }

  // Find pair-values with row-count exactly 2; build per-cell clear masks.
  uint32_t clearbits[9];
#pragma unroll
  for (int w = 0; w < 9; ++w) clearbits[w] = 0u;
#pragma unroll
  for (int w1 = 0; w1 < 9; ++w1) {
    uint32_t c1 = cand[w1];
    if (__popc(c1) != 2) continue;
    int cnt = 0;
#pragma unroll
    for (int w2 = 0; w2 < 9; ++w2) cnt += (cand[w2] == c1) ? 1 : 0;
    if (cnt == 2) {
#pragma unroll
      for (int w = 0; w < 9; ++w)
        if (cand[w] != c1) clearbits[w] |= c1;
    }
  }

  // keep[w] = surviving digits; write 1.0f/0.0f bit patterns.
  uint32_t keep[9];
#pragma unroll
  for (int w = 0; w < 9; ++w) keep[w] = cand[w] & ~clearbits[w];

  uint32_t* obase = out + (size_t)b * 729 + h * 9;
#pragma unroll
  for (int d = 0; d < 9; ++d) {
    uint32_t tmp[9];
#pragma unroll
    for (int w = 0; w < 9; ++w)
      tmp[w] = ((keep[w] >> d) & 1u) ? 0x3F800000u : 0u;
    __builtin_memcpy(obase + d * 81, tmp, 36);
  }
}

extern "C" void kernel_launch(void* const* d_in, const int* in_sizes, int n_in,
                              void* d_out, int out_size, void* d_ws, size_t ws_size,
                              hipStream_t stream) {
  const uint32_t* in = (const uint32_t*)d_in[0];  // mask, float32 binary
  uint32_t* out = (uint32_t*)d_out;               // float32 out, bit-patterns
  int B = in_sizes[0] / 729;
  int nrows = B * 9;
  const int threads = 256;
  int blocks = (nrows + threads - 1) / threads;
  sudoku_rows_kernel<<<blocks, threads, 0, stream>>>(in, out, nrows);
}